// Round 3
// baseline (538.137 us; speedup 1.0000x reference)
//
#include <hip/hip_runtime.h>
#include <stdint.h>

typedef unsigned short ushort_t;
typedef __attribute__((ext_vector_type(8))) short short8;   // 8 x bf16 (4 VGPRs)
typedef __attribute__((ext_vector_type(4))) float floatx4;  // MFMA accum

#define SEQ_N 2048
#define SEQ_M 2048
#define DIM_D 128
#define DIM_V 128
#define BR 128   // Q rows per workgroup (4 waves x 32 rows)
#define BC 64    // K/V cols per tile

// LDS layout (ushort elements). Strides padded to keep b128 reads bank-uniform.
#define KS_LD 136   // K tile row stride (64 x 136)
#define VS_LD 72    // V^T tile row stride (128 x 72)
#define PS_LD 72    // P tile row stride (128 x 72)
#define K0 0
#define V0 8704     // 64*136
#define P0 17920    // V0 + 128*72
#define SMEM_ELEMS 27136   // 54272 B

#if __has_builtin(__builtin_amdgcn_exp2f)
#define EXP2F(x) __builtin_amdgcn_exp2f(x)
#else
#define EXP2F(x) exp2f(x)
#endif

// DPP row_ror reduction across the 16-lane row group (VALU pipe, no LDS traffic)
template <int CTRL>
__device__ __forceinline__ float dpp_f(float x) {
  int xi = __builtin_bit_cast(int, x);
  int yi = __builtin_amdgcn_update_dpp(xi, xi, CTRL, 0xf, 0xf, false);
  return __builtin_bit_cast(float, yi);
}
__device__ __forceinline__ float rowmax16(float x) {
  x = fmaxf(x, dpp_f<0x128>(x));  // row_ror:8
  x = fmaxf(x, dpp_f<0x124>(x));  // row_ror:4
  x = fmaxf(x, dpp_f<0x122>(x));  // row_ror:2
  x = fmaxf(x, dpp_f<0x121>(x));  // row_ror:1
  return x;
}
__device__ __forceinline__ float rowsum16(float x) {
  x += dpp_f<0x128>(x);
  x += dpp_f<0x124>(x);
  x += dpp_f<0x122>(x);
  x += dpp_f<0x121>(x);
  return x;
}

__device__ __forceinline__ ushort_t f2bf(float f) {
  uint32_t u = __builtin_bit_cast(uint32_t, f);
  return (ushort_t)((u + 0x8000u) >> 16);
}

// Load 8 consecutive fp32 elements at element offset off, convert to bf16.
__device__ __forceinline__ void load8f(const float* __restrict__ base, size_t off,
                                       ushort_t* dst) {
  const float* p = base + off;
  float4 f0 = *(const float4*)p;
  float4 f1 = *(const float4*)(p + 4);
  dst[0] = f2bf(f0.x); dst[1] = f2bf(f0.y); dst[2] = f2bf(f0.z); dst[3] = f2bf(f0.w);
  dst[4] = f2bf(f1.x); dst[5] = f2bf(f1.y); dst[6] = f2bf(f1.z); dst[7] = f2bf(f1.w);
}

__global__ __launch_bounds__(256, 2)
void fa_kernel(const float* __restrict__ Q, const float* __restrict__ K,
               const float* __restrict__ Vg, const int* __restrict__ kpl,
               const int* __restrict__ amask, float* __restrict__ Out) {
  __shared__ __align__(16) ushort_t smem[SMEM_ELEMS];

  const int tid  = threadIdx.x;
  const int lane = tid & 63;
  const int w    = tid >> 6;    // wave 0..3
  const int qd   = lane >> 4;   // quad 0..3
  const int nn   = lane & 15;   // MFMA m/n index

  const int bx = blockIdx.x;
  const int b  = bx >> 4;       // batch
  const int rt = bx & 15;       // Q row-tile
  const int r0 = rt * BR;

  const int flag   = amask[0];
  const int pad    = kpl[b];
  const int mlimit = SEQ_M - pad;   // keys j >= mlimit are zeroed (score=0, V kept)

  // scale * log2(e): softmax computed as exp2(s*c1 - m)
  const float c1 = 0.08838834764831845f * 1.4426950408889634f;

  // staging thread mapping: oct = v/d octet, jq -> 4 consecutive K/V rows
  const int oct = tid & 15;
  const int jq  = tid >> 4;   // 0..15
  const int j0  = jq * 4;

  const size_t qoff = ((size_t)b * SEQ_N + (r0 + w * 32)) * DIM_D;
  const size_t koff = (size_t)b * SEQ_M * DIM_D;
  const size_t voff = (size_t)b * SEQ_M * DIM_V;

  // ---- Q fragments (A-layout, bf16), held in registers for the whole kernel ----
  short8 qf[2][4];
  {
    union { short8 v; ushort_t u[8]; } tmp;
#pragma unroll
    for (int r2 = 0; r2 < 2; ++r2)
#pragma unroll
      for (int ks = 0; ks < 4; ++ks) {
        load8f(Q, qoff + (size_t)(r2 * 16 + nn) * DIM_D + ks * 32 + qd * 8, tmp.u);
        qf[r2][ks] = tmp.v;
      }
  }

  floatx4 o0[8], o1[8];
#pragma unroll
  for (int vt = 0; vt < 8; ++vt) { o0[vt] = (floatx4)0.0f; o1[vt] = (floatx4)0.0f; }
  float m0[4], m1[4], l0[4], l1[4];
#pragma unroll
  for (int r = 0; r < 4; ++r) { m0[r] = m1[r] = -3.0e38f; l0[r] = l1[r] = 0.0f; }

  const int i0w = r0 + w * 32;   // first Q row owned by this wave
  const int ntiles = flag ? (rt * 2 + 2) : (SEQ_M / BC);

  for (int jt = 0; jt < ntiles; ++jt) {
    const int jbase = jt * BC;
    __syncthreads();   // prev iteration done reading K/V LDS

    // ---- stage K tile [64 x 128] row-major (bf16), zero padded keys ----
    {
      alignas(16) ushort_t kt[8];
#pragma unroll
      for (int r = 0; r < 4; ++r) {
        int j = j0 + r;
        if (jbase + j < mlimit) {
          load8f(K, koff + (size_t)(jbase + j) * DIM_D + oct * 8, kt);
        } else {
#pragma unroll
          for (int q = 0; q < 8; ++q) kt[q] = 0;
        }
        *(uint4*)(smem + K0 + j * KS_LD + oct * 8) = *(const uint4*)kt;
      }
      // ---- stage V tile transposed: Vs[v][j] = V[jbase+j][v] ----
      alignas(16) ushort_t cs[4][8];
#pragma unroll
      for (int r = 0; r < 4; ++r)
        load8f(Vg, voff + (size_t)(jbase + j0 + r) * DIM_V + oct * 8, cs[r]);
#pragma unroll
      for (int slot = 0; slot < 8; ++slot) {
        int vv = (slot + oct) & 7;   // rotation keeps writes ~2-way across banks
        uint32_t lo = (uint32_t)cs[0][vv] | ((uint32_t)cs[1][vv] << 16);
        uint32_t hi = (uint32_t)cs[2][vv] | ((uint32_t)cs[3][vv] << 16);
        uint2 dv; dv.x = lo; dv.y = hi;
        *(uint2*)(smem + V0 + (oct * 8 + vv) * VS_LD + j0) = dv;
      }
    }
    __syncthreads();

    const bool act0 = (!flag) || (jbase <= i0w + 15);
    const bool act1 = (!flag) || (jbase <= i0w + 31);
    if (!act1) continue;   // whole wave fully masked this tile (wave-uniform)

    // ---- S = Q K^T : each K B-frag feeds both row-tiles ----
    floatx4 s0[4], s1[4];
#pragma unroll
    for (int ct = 0; ct < 4; ++ct) { s0[ct] = (floatx4)0.0f; s1[ct] = (floatx4)0.0f; }
#pragma unroll
    for (int ks = 0; ks < 4; ++ks) {
#pragma unroll
      for (int ct = 0; ct < 4; ++ct) {
        short8 bf = *(const short8*)(smem + K0 + (ct * 16 + nn) * KS_LD + ks * 32 + qd * 8);
        if (act0) s0[ct] = __builtin_amdgcn_mfma_f32_16x16x32_bf16(qf[0][ks], bf, s0[ct], 0, 0, 0);
        s1[ct] = __builtin_amdgcn_mfma_f32_16x16x32_bf16(qf[1][ks], bf, s1[ct], 0, 0, 0);
      }
    }

    // ---- online softmax per 16-row tile; write P (bf16) to per-wave LDS ----
    auto softmax_rt = [&](floatx4* s, float* mm, float* ll, floatx4* oo,
                          int rbase, int i0) {
      float t[4][4];
      const bool needmask = flag && (jbase + BC - 1 > i0);
#pragma unroll
      for (int ct = 0; ct < 4; ++ct) {
#pragma unroll
        for (int r = 0; r < 4; ++r) {
          float tv = s[ct][r] * c1;
          if (needmask) {
            int jgl = jbase + ct * 16 + nn;
            int igl = i0 + qd * 4 + r;
            if (jgl > igl) tv = -3.0e38f;
          }
          t[ct][r] = tv;
        }
      }
#pragma unroll
      for (int r = 0; r < 4; ++r) {
        float mr = fmaxf(fmaxf(t[0][r], t[1][r]), fmaxf(t[2][r], t[3][r]));
        mr = rowmax16(mr);
        float mn = fmaxf(mm[r], mr);
        float alpha = EXP2F(mm[r] - mn);
        mm[r] = mn;
        float ps = 0.0f;
#pragma unroll
        for (int ct = 0; ct < 4; ++ct) {
          float p = EXP2F(t[ct][r] - mn);
          t[ct][r] = p;
          ps += p;
        }
        ll[r] = ll[r] * alpha + ps;   // per-lane partial; reduced in epilogue
#pragma unroll
        for (int vt = 0; vt < 8; ++vt) oo[vt][r] *= alpha;
      }
#pragma unroll
      for (int ct = 0; ct < 4; ++ct)
#pragma unroll
        for (int r = 0; r < 4; ++r)
          smem[P0 + (rbase + qd * 4 + r) * PS_LD + ct * 16 + nn] = f2bf(t[ct][r]);
    };
    if (act0) softmax_rt(s0, m0, l0, o0, w * 32, i0w);
    softmax_rt(s1, m1, l1, o1, w * 32 + 16, i0w + 16);

    // ---- O += P V : shared V B-frags feed both row-tiles ----
#pragma unroll
    for (int ks2 = 0; ks2 < 2; ++ks2) {
      short8 a0, a1;
      if (act0) a0 = *(const short8*)(smem + P0 + (w * 32 + nn) * PS_LD + ks2 * 32 + qd * 8);
      a1 = *(const short8*)(smem + P0 + (w * 32 + 16 + nn) * PS_LD + ks2 * 32 + qd * 8);
#pragma unroll
      for (int vt = 0; vt < 8; ++vt) {
        short8 vb = *(const short8*)(smem + V0 + (vt * 16 + nn) * VS_LD + ks2 * 32 + qd * 8);
        if (act0) o0[vt] = __builtin_amdgcn_mfma_f32_16x16x32_bf16(a0, vb, o0[vt], 0, 0, 0);
        o1[vt] = __builtin_amdgcn_mfma_f32_16x16x32_bf16(a1, vb, o1[vt], 0, 0, 0);
      }
    }
  }

  // ---- epilogue: reduce l across the 16-lane row group, normalize, store fp32 ----
#pragma unroll
  for (int r = 0; r < 4; ++r) { l0[r] = rowsum16(l0[r]); l1[r] = rowsum16(l1[r]); }

  // Direct register->global stores. Per instruction, each 16-lane group writes
  // 64B contiguous (rows differ across quads): 4x64B segments per wave store.
  float* Ob = Out + ((size_t)b * SEQ_N + i0w) * DIM_V;
#pragma unroll
  for (int r2 = 0; r2 < 2; ++r2) {
    float*   ll = r2 ? l1 : l0;
    floatx4* oo = r2 ? o1 : o0;
#pragma unroll
    for (int r = 0; r < 4; ++r) {
      float inv = 1.0f / ll[r];
      int row = r2 * 16 + qd * 4 + r;
#pragma unroll
      for (int vt = 0; vt < 8; ++vt)
        Ob[(size_t)row * DIM_V + vt * 16 + nn] = oo[vt][r] * inv;
    }
  }
}

extern "C" void kernel_launch(void* const* d_in, const int* in_sizes, int n_in,
                              void* d_out, int out_size, void* d_ws, size_t ws_size,
                              hipStream_t stream) {
  const float* Q   = (const float*)d_in[0];
  const float* K   = (const float*)d_in[1];
  const float* V   = (const float*)d_in[2];
  const int* kpl   = (const int*)d_in[3];
  const int* amask = (const int*)d_in[4];
  float* O         = (float*)d_out;

  const int B = in_sizes[3];                  // 16 batches
  dim3 grid(B * (SEQ_N / BR));                // 256 workgroups
  dim3 block(256);
  hipLaunchKernelGGL(fa_kernel, grid, block, 0, stream, Q, K, V, kpl, amask, O);
}

// Round 5
// 183.931 us; speedup vs baseline: 2.9258x; 2.9258x over previous
//
#include <hip/hip_runtime.h>
#include <stdint.h>

typedef unsigned short ushort_t;
typedef __attribute__((ext_vector_type(8))) short short8;   // 8 x bf16 (4 VGPRs)
typedef __attribute__((ext_vector_type(4))) float floatx4;  // MFMA accum

#define SEQ_N 2048
#define SEQ_M 2048
#define DIM_D 128
#define DIM_V 128
#define BC 64    // keys per tile
// Each wg: 4 waves x 16 Q-rows = 64 rows per phase; phases (rt, 31-rt) -> 33 tiles/wg uniform.

// LDS layout (ushort elements). All accesses at hardware-minimum bank occupancy.
#define KS_LD 136          // K tile row stride (64 x 136), double-buffered
#define VS_LD 72           // V^T tile row stride (128 x 72), double-buffered, row-swizzled
#define PS_LD 72           // P tile row stride (64 x 72)
#define KB(i) ((i) * 8704)
#define VB(i) (17408 + (i) * 9216)
#define P0 35840
#define SMEM_ELEMS 40448   // 80896 B

#if __has_builtin(__builtin_amdgcn_exp2f)
#define EXP2F(x) __builtin_amdgcn_exp2f(x)
#else
#define EXP2F(x) exp2f(x)
#endif

template <int CTRL>
__device__ __forceinline__ float dpp_f(float x) {
  int xi = __builtin_bit_cast(int, x);
  int yi = __builtin_amdgcn_update_dpp(xi, xi, CTRL, 0xf, 0xf, false);
  return __builtin_bit_cast(float, yi);
}
__device__ __forceinline__ float rowmax16(float x) {
  x = fmaxf(x, dpp_f<0x128>(x));
  x = fmaxf(x, dpp_f<0x124>(x));
  x = fmaxf(x, dpp_f<0x122>(x));
  x = fmaxf(x, dpp_f<0x121>(x));
  return x;
}
__device__ __forceinline__ float rowsum16(float x) {
  x += dpp_f<0x128>(x);
  x += dpp_f<0x124>(x);
  x += dpp_f<0x122>(x);
  x += dpp_f<0x121>(x);
  return x;
}

__device__ __forceinline__ ushort_t f2bf(float f) {
  uint32_t u = __builtin_bit_cast(uint32_t, f);
  return (ushort_t)((u + 0x8000u) >> 16);
}
__device__ __forceinline__ uint32_t pack2(float a, float bq) {
  return (uint32_t)f2bf(a) | ((uint32_t)f2bf(bq) << 16);
}

// V^T physical-row swizzle: p(v) = 8*(v>>3) + ((v + (v>>3)) & 7).
// Bijective (per-8-block rotation). Write side (v=8*oct+q): p%8=(oct+q)&7 ->
// uniform-4/bank (b64 minimum). Read side (v=16*vt+nn): p%8=(2vt+nn+(nn>>3))&7
// -> uniform-8/bank, 4-aligned starts (b128 minimum).

__global__ __launch_bounds__(256, 1)
void fa_kernel(const float* __restrict__ Q, const float* __restrict__ K,
               const float* __restrict__ Vg, const int* __restrict__ kpl,
               const int* __restrict__ amask, float* __restrict__ Out) {
  __shared__ __align__(16) ushort_t smem[SMEM_ELEMS];

  const int tid  = threadIdx.x;
  const int lane = tid & 63;
  const int w    = tid >> 6;    // wave 0..3
  const int qd   = lane >> 4;   // quad 0..3
  const int nn   = lane & 15;   // MFMA m/n index

  const int bx = blockIdx.x;
  const int b  = bx & 15;       // batch (bx%8 == b%8 -> same-batch wgs share XCD L2)
  const int pp = bx >> 4;       // pair id 0..15 -> phases rt = pp, 31-pp

  const int flag   = amask[0];
  const int mlimit = SEQ_M - kpl[b];   // keys j >= mlimit are zeroed (score=0)

  const float c1 = 0.08838834764831845f * 1.4426950408889634f;  // scale*log2e

  // staging mapping: oct = 32B column chunk, j0 -> 4 consecutive K/V rows
  const int oct = tid & 15;
  const int j0  = (tid >> 4) * 4;
  const int hh  = nn >> 3;      // read-side swizzle helpers
  const int rb  = 8 * hh;

  const size_t koff = (size_t)b * SEQ_M * DIM_D;
  const size_t voff = (size_t)b * SEQ_M * DIM_V;

#pragma unroll 1
  for (int ph = 0; ph < 2; ++ph) {
    const int rt  = ph ? (31 - pp) : pp;
    const int r0  = rt * 64;
    const int i0w = r0 + w * 16;                    // wave's first Q row
    const int ntiles = flag ? (rt + 1) : (SEQ_M / BC);

    // ---- Q fragments (A-layout, bf16) ----
    short8 qf[4];
    {
      const float* Qb = Q + ((size_t)b * SEQ_N + (size_t)(i0w + nn)) * DIM_D;
      union { short8 v; ushort_t u[8]; } t;
#pragma unroll
      for (int ks = 0; ks < 4; ++ks) {
        const float* p = Qb + ks * 32 + qd * 8;
        float4 f0 = *(const float4*)p, f1 = *(const float4*)(p + 4);
        t.u[0]=f2bf(f0.x); t.u[1]=f2bf(f0.y); t.u[2]=f2bf(f0.z); t.u[3]=f2bf(f0.w);
        t.u[4]=f2bf(f1.x); t.u[5]=f2bf(f1.y); t.u[6]=f2bf(f1.z); t.u[7]=f2bf(f1.w);
        qf[ks] = t.v;
      }
    }

    floatx4 o[8];
#pragma unroll
    for (int vt = 0; vt < 8; ++vt) o[vt] = (floatx4)0.0f;
    float m[4], l[4];
#pragma unroll
    for (int r = 0; r < 4; ++r) { m[r] = -3.0e38f; l[r] = 0.0f; }

    // prefetch registers (raw fp32 so loads stay in flight during compute)
    float4 kr[4][2], vr[4][2];

    auto stage_load = [&](int jt) {
      const int jbase = jt * BC;
#pragma unroll
      for (int r = 0; r < 4; ++r) {
        const float* kp = K  + koff + (size_t)(jbase + j0 + r) * DIM_D + oct * 8;
        kr[r][0] = *(const float4*)kp;  kr[r][1] = *(const float4*)(kp + 4);
        const float* vp = Vg + voff + (size_t)(jbase + j0 + r) * DIM_V + oct * 8;
        vr[r][0] = *(const float4*)vp;  vr[r][1] = *(const float4*)(vp + 4);
      }
    };

    auto stage_write = [&](int buf, int jt) {
      const int jbase = jt * BC;
      const int kb = KB(buf), vb = VB(buf);
#pragma unroll
      for (int r = 0; r < 4; ++r) {     // K rows, zero the padded keys
        uint4 kw;
        kw.x = pack2(kr[r][0].x, kr[r][0].y);
        kw.y = pack2(kr[r][0].z, kr[r][0].w);
        kw.z = pack2(kr[r][1].x, kr[r][1].y);
        kw.w = pack2(kr[r][1].z, kr[r][1].w);
        if (jbase + j0 + r >= mlimit) kw = make_uint4(0u, 0u, 0u, 0u);
        *(uint4*)(smem + kb + (j0 + r) * KS_LD + oct * 8) = kw;
      }
      // V transpose: static register indexing only (q is an unrolled constant)
      ushort_t vs[4][8];
#pragma unroll
      for (int r = 0; r < 4; ++r) {
        vs[r][0]=f2bf(vr[r][0].x); vs[r][1]=f2bf(vr[r][0].y);
        vs[r][2]=f2bf(vr[r][0].z); vs[r][3]=f2bf(vr[r][0].w);
        vs[r][4]=f2bf(vr[r][1].x); vs[r][5]=f2bf(vr[r][1].y);
        vs[r][6]=f2bf(vr[r][1].z); vs[r][7]=f2bf(vr[r][1].w);
      }
#pragma unroll
      for (int q = 0; q < 8; ++q) {
        const int p = 8 * oct + ((oct + q) & 7);   // swizzled physical row of v=8*oct+q
        uint2 dv;
        dv.x = (uint32_t)vs[0][q] | ((uint32_t)vs[1][q] << 16);
        dv.y = (uint32_t)vs[2][q] | ((uint32_t)vs[3][q] << 16);
        *(uint2*)(smem + vb + p * VS_LD + j0) = dv;
      }
    };

    // ---- prologue: stage tile 0 ----
    stage_load(0);
    stage_write(0, 0);
    __syncthreads();

#pragma unroll 1
    for (int jt = 0; jt < ntiles; ++jt) {
      const int cur  = jt & 1;
      const bool more = (jt + 1) < ntiles;
      const int jbase = jt * BC;
      if (more) stage_load(jt + 1);   // loads in flight during compute

      const int kb = KB(cur), vb = VB(cur);

      // ---- S = Q K^T ----
      floatx4 s[4];
#pragma unroll
      for (int ct = 0; ct < 4; ++ct) s[ct] = (floatx4)0.0f;
#pragma unroll
      for (int ks = 0; ks < 4; ++ks) {
#pragma unroll
        for (int ct = 0; ct < 4; ++ct) {
          short8 bf = *(const short8*)(smem + kb + (ct * 16 + nn) * KS_LD + ks * 32 + qd * 8);
          s[ct] = __builtin_amdgcn_mfma_f32_16x16x32_bf16(qf[ks], bf, s[ct], 0, 0, 0);
        }
      }

      // ---- online softmax (16 rows/wave), P -> per-wave LDS ----
      {
        float t[4][4];
        const bool needmask = flag && (jbase + BC - 1 > i0w);
#pragma unroll
        for (int ct = 0; ct < 4; ++ct)
#pragma unroll
          for (int r = 0; r < 4; ++r) {
            float tv = s[ct][r] * c1;
            if (needmask) {
              int jgl = jbase + ct * 16 + nn;
              int igl = i0w + qd * 4 + r;
              if (jgl > igl) tv = -3.0e38f;
            }
            t[ct][r] = tv;
          }
#pragma unroll
        for (int r = 0; r < 4; ++r) {
          float mr = fmaxf(fmaxf(t[0][r], t[1][r]), fmaxf(t[2][r], t[3][r]));
          mr = rowmax16(mr);
          float mn = fmaxf(m[r], mr);
          float alpha = EXP2F(m[r] - mn);
          m[r] = mn;
          float ps = 0.0f;
#pragma unroll
          for (int ct = 0; ct < 4; ++ct) {
            float p = EXP2F(t[ct][r] - mn);
            t[ct][r] = p;
            ps += p;
          }
          l[r] = l[r] * alpha + ps;   // per-lane partial; reduced in epilogue
#pragma unroll
          for (int vt = 0; vt < 8; ++vt) o[vt][r] *= alpha;
        }
#pragma unroll
        for (int ct = 0; ct < 4; ++ct)
#pragma unroll
          for (int r = 0; r < 4; ++r)
            smem[P0 + (w * 16 + qd * 4 + r) * PS_LD + ct * 16 + nn] = f2bf(t[ct][r]);
      }

      // ---- O += P V (P round-trips per-wave LDS; V^T rows swizzled) ----
#pragma unroll
      for (int ks2 = 0; ks2 < 2; ++ks2) {
        short8 a = *(const short8*)(smem + P0 + (w * 16 + nn) * PS_LD + ks2 * 32 + qd * 8);
#pragma unroll
        for (int vt = 0; vt < 8; ++vt) {
          const int p = 16 * vt + rb + ((2 * vt + nn + hh) & 7);
          short8 vbf = *(const short8*)(smem + vb + p * VS_LD + ks2 * 32 + qd * 8);
          o[vt] = __builtin_amdgcn_mfma_f32_16x16x32_bf16(a, vbf, o[vt], 0, 0, 0);
        }
      }

      if (more) stage_write(cur ^ 1, jt + 1);
      __syncthreads();
    }

    // ---- epilogue: reduce l, normalize, direct fp32 stores (64B/16-lane segments) ----
#pragma unroll
    for (int r = 0; r < 4; ++r) l[r] = rowsum16(l[r]);
    float* Ob = Out + ((size_t)b * SEQ_N + i0w) * DIM_V;
#pragma unroll
    for (int r = 0; r < 4; ++r) {
      float inv = 1.0f / l[r];
      int row = qd * 4 + r;
#pragma unroll
      for (int vt = 0; vt < 8; ++vt)
        Ob[(size_t)row * DIM_V + vt * 16 + nn] = o[vt][r] * inv;
    }
    // epilogue touches no LDS; next phase's first stage_write is safe after the
    // K-loop's final barrier.
  }
}

extern "C" void kernel_launch(void* const* d_in, const int* in_sizes, int n_in,
                              void* d_out, int out_size, void* d_ws, size_t ws_size,
                              hipStream_t stream) {
  const float* Q   = (const float*)d_in[0];
  const float* K   = (const float*)d_in[1];
  const float* V   = (const float*)d_in[2];
  const int* kpl   = (const int*)d_in[3];
  const int* amask = (const int*)d_in[4];
  float* O         = (float*)d_out;

  const int B = in_sizes[3];          // 16 batches
  dim3 grid(B * 16);                  // 16 pairs x 16 batches = 256 wgs (1/CU), balanced
  dim3 block(256);
  hipLaunchKernelGGL(fa_kernel, grid, block, 0, stream, Q, K, V, kpl, amask, O);
}

// Round 6
// 145.525 us; speedup vs baseline: 3.6979x; 1.2639x over previous
//
#include <hip/hip_runtime.h>
#include <stdint.h>

typedef unsigned short ushort_t;
typedef __attribute__((ext_vector_type(8))) short short8;   // 8 x bf16 (4 VGPRs)
typedef __attribute__((ext_vector_type(4))) float floatx4;  // MFMA accum

#define SEQ_N 2048
#define SEQ_M 2048
#define DIM_D 128
#define DIM_V 128
#define BC 64    // keys per tile

// LDS layout (ushort elements) — identical to the verified round-5 layout.
#define KS_LD 136          // K tile row stride (64 x 136), double-buffered
#define VS_LD 72           // V^T tile row stride (128 x 72), double-buffered, row-swizzled
#define PS_LD 72           // P tile row stride (64 x 72)
#define KB(i) ((i) * 8704)
#define VB(i) (17408 + (i) * 9216)
#define P0 35840
#define SMEM_ELEMS 40448   // 80896 B -> exactly 2 wgs/CU (161792 <= 163840)

// workspace layout (floats): partials for split rows (rt >= 16)
#define WS_O_FLOATS (256 * 2 * 64 * 128)          // 4194304
#define WS_M_OFF    WS_O_FLOATS
#define WS_L_OFF    (WS_O_FLOATS + 32768)
#define WS_FLOATS   (WS_O_FLOATS + 65536)         // 4259840 floats = 17039360 B

#if __has_builtin(__builtin_amdgcn_exp2f)
#define EXP2F(x) __builtin_amdgcn_exp2f(x)
#else
#define EXP2F(x) exp2f(x)
#endif

template <int CTRL>
__device__ __forceinline__ float dpp_f(float x) {
  int xi = __builtin_bit_cast(int, x);
  int yi = __builtin_amdgcn_update_dpp(xi, xi, CTRL, 0xf, 0xf, false);
  return __builtin_bit_cast(float, yi);
}
__device__ __forceinline__ float rowmax16(float x) {
  x = fmaxf(x, dpp_f<0x128>(x));
  x = fmaxf(x, dpp_f<0x124>(x));
  x = fmaxf(x, dpp_f<0x122>(x));
  x = fmaxf(x, dpp_f<0x121>(x));
  return x;
}
__device__ __forceinline__ float rowsum16(float x) {
  x += dpp_f<0x128>(x);
  x += dpp_f<0x124>(x);
  x += dpp_f<0x122>(x);
  x += dpp_f<0x121>(x);
  return x;
}

__device__ __forceinline__ ushort_t f2bf(float f) {
  uint32_t u = __builtin_bit_cast(uint32_t, f);
  return (ushort_t)((u + 0x8000u) >> 16);
}
// pack two fp32 -> bf16 pair in ONE v_perm (3 VALU total, bit-identical to f2bf pair)
__device__ __forceinline__ uint32_t bfpack(float lo, float hi) {
  uint32_t a = __builtin_bit_cast(uint32_t, lo) + 0x8000u;
  uint32_t b = __builtin_bit_cast(uint32_t, hi) + 0x8000u;
  return __builtin_amdgcn_perm(b, a, 0x07060302u);  // {b[31:16], a[31:16]}
}

// One flash chunk: Q rows [rt*64, rt*64+64), key tiles [jt_lo, jt_hi).
// direct: normalized store to Out. else: unnormalized (O,m,l) partial to ws chunk c.
__device__ __forceinline__ void process_chunk(
    const float* __restrict__ Q, const float* __restrict__ K,
    const float* __restrict__ Vg, float* __restrict__ Out,
    float* __restrict__ ws, ushort_t* __restrict__ smem,
    int b, int rt, int jt_lo, int jt_hi, int mlimit, int flag, int c, bool direct) {
  const int tid  = threadIdx.x;
  const int lane = tid & 63;
  const int w    = tid >> 6;
  const int qd   = lane >> 4;
  const int nn   = lane & 15;

  const float c1 = 0.08838834764831845f * 1.4426950408889634f;  // scale*log2e

  const int oct = tid & 15;
  const int j0  = (tid >> 4) * 4;
  const int hh  = nn >> 3;
  const int rb  = 8 * hh;

  const int i0w = rt * 64 + w * 16;
  const size_t koff = (size_t)b * SEQ_M * DIM_D;
  const size_t voff = (size_t)b * SEQ_M * DIM_V;

  // ---- Q fragments (A-layout, bf16) ----
  short8 qf[4];
  {
    const float* Qb = Q + ((size_t)b * SEQ_N + (size_t)(i0w + nn)) * DIM_D;
    union { short8 v; uint32_t u32[4]; } t;
#pragma unroll
    for (int ks = 0; ks < 4; ++ks) {
      const float* p = Qb + ks * 32 + qd * 8;
      float4 f0 = *(const float4*)p, f1 = *(const float4*)(p + 4);
      t.u32[0] = bfpack(f0.x, f0.y);
      t.u32[1] = bfpack(f0.z, f0.w);
      t.u32[2] = bfpack(f1.x, f1.y);
      t.u32[3] = bfpack(f1.z, f1.w);
      qf[ks] = t.v;
    }
  }

  floatx4 o[8];
#pragma unroll
  for (int vt = 0; vt < 8; ++vt) o[vt] = (floatx4)0.0f;
  float m[4], l[4];
#pragma unroll
  for (int r = 0; r < 4; ++r) { m[r] = -3.0e38f; l[r] = 0.0f; }

  float4 kr[4][2], vr[4][2];   // register prefetch (fp32, loads in flight over compute)

  auto stage_load = [&](int jt) {
    const int jbase = jt * BC;
#pragma unroll
    for (int r = 0; r < 4; ++r) {
      const float* kp = K  + koff + (size_t)(jbase + j0 + r) * DIM_D + oct * 8;
      kr[r][0] = *(const float4*)kp;  kr[r][1] = *(const float4*)(kp + 4);
      const float* vp = Vg + voff + (size_t)(jbase + j0 + r) * DIM_V + oct * 8;
      vr[r][0] = *(const float4*)vp;  vr[r][1] = *(const float4*)(vp + 4);
    }
  };

  auto stage_write = [&](int buf, int jt) {
    const int jbase = jt * BC;
    const int kb = KB(buf), vb = VB(buf);
#pragma unroll
    for (int r = 0; r < 4; ++r) {     // K rows, zero the padded keys
      uint4 kw;
      kw.x = bfpack(kr[r][0].x, kr[r][0].y);
      kw.y = bfpack(kr[r][0].z, kr[r][0].w);
      kw.z = bfpack(kr[r][1].x, kr[r][1].y);
      kw.w = bfpack(kr[r][1].z, kr[r][1].w);
      if (jbase + j0 + r >= mlimit) kw = make_uint4(0u, 0u, 0u, 0u);
      *(uint4*)(smem + kb + (j0 + r) * KS_LD + oct * 8) = kw;
    }
    // V^T with bijective row swizzle p(v) = 8*(v>>3) + ((v + (v>>3)) & 7)
    float vc[4][8];
#pragma unroll
    for (int r = 0; r < 4; ++r) {
      vc[r][0]=vr[r][0].x; vc[r][1]=vr[r][0].y; vc[r][2]=vr[r][0].z; vc[r][3]=vr[r][0].w;
      vc[r][4]=vr[r][1].x; vc[r][5]=vr[r][1].y; vc[r][6]=vr[r][1].z; vc[r][7]=vr[r][1].w;
    }
#pragma unroll
    for (int q = 0; q < 8; ++q) {
      const int p = 8 * oct + ((oct + q) & 7);   // physical row of v = 8*oct + q
      uint2 dv;
      dv.x = bfpack(vc[0][q], vc[1][q]);
      dv.y = bfpack(vc[2][q], vc[3][q]);
      *(uint2*)(smem + vb + p * VS_LD + j0) = dv;
    }
  };

  // ---- prologue ----
  stage_load(jt_lo);
  stage_write(0, jt_lo);
  __syncthreads();

  const int len = jt_hi - jt_lo;
#pragma unroll 1
  for (int t = 0; t < len; ++t) {
    const int jt = jt_lo + t;
    const int cur = t & 1;
    const bool more = (t + 1) < len;
    const int jbase = jt * BC;
    if (more) stage_load(jt + 1);

    const int kb = KB(cur), vb = VB(cur);

    // ---- S = Q K^T ----
    floatx4 s[4];
#pragma unroll
    for (int ct = 0; ct < 4; ++ct) s[ct] = (floatx4)0.0f;
#pragma unroll
    for (int ks = 0; ks < 4; ++ks) {
#pragma unroll
      for (int ct = 0; ct < 4; ++ct) {
        short8 bf = *(const short8*)(smem + kb + (ct * 16 + nn) * KS_LD + ks * 32 + qd * 8);
        s[ct] = __builtin_amdgcn_mfma_f32_16x16x32_bf16(qf[ks], bf, s[ct], 0, 0, 0);
      }
    }

    // ---- online softmax (16 rows/wave), P -> per-wave LDS ----
    {
      float tt[4][4];
      const bool needmask = flag && (jbase + BC - 1 > i0w);
#pragma unroll
      for (int ct = 0; ct < 4; ++ct)
#pragma unroll
        for (int r = 0; r < 4; ++r) {
          float tv = s[ct][r] * c1;
          if (needmask) {
            int jgl = jbase + ct * 16 + nn;
            int igl = i0w + qd * 4 + r;
            if (jgl > igl) tv = -3.0e38f;
          }
          tt[ct][r] = tv;
        }
#pragma unroll
      for (int r = 0; r < 4; ++r) {
        float mr = fmaxf(fmaxf(tt[0][r], tt[1][r]), fmaxf(tt[2][r], tt[3][r]));
        mr = rowmax16(mr);
        float mn = fmaxf(m[r], mr);
        float alpha = EXP2F(m[r] - mn);
        m[r] = mn;
        float ps = 0.0f;
#pragma unroll
        for (int ct = 0; ct < 4; ++ct) {
          float p = EXP2F(tt[ct][r] - mn);
          tt[ct][r] = p;
          ps += p;
        }
        l[r] = l[r] * alpha + ps;
#pragma unroll
        for (int vt = 0; vt < 8; ++vt) o[vt][r] *= alpha;
      }
#pragma unroll
      for (int ct = 0; ct < 4; ++ct)
#pragma unroll
        for (int r = 0; r < 4; ++r)
          smem[P0 + (w * 16 + qd * 4 + r) * PS_LD + ct * 16 + nn] = f2bf(tt[ct][r]);
    }

    // ---- O += P V ----
#pragma unroll
    for (int ks2 = 0; ks2 < 2; ++ks2) {
      short8 a = *(const short8*)(smem + P0 + (w * 16 + nn) * PS_LD + ks2 * 32 + qd * 8);
#pragma unroll
      for (int vt = 0; vt < 8; ++vt) {
        const int p = 16 * vt + rb + ((2 * vt + nn + hh) & 7);
        short8 vbf = *(const short8*)(smem + vb + p * VS_LD + ks2 * 32 + qd * 8);
        o[vt] = __builtin_amdgcn_mfma_f32_16x16x32_bf16(a, vbf, o[vt], 0, 0, 0);
      }
    }

    if (more) stage_write(cur ^ 1, jt + 1);
    __syncthreads();
  }

  // ---- epilogue ----
#pragma unroll
  for (int r = 0; r < 4; ++r) l[r] = rowsum16(l[r]);

  if (direct) {
    float* Ob = Out + ((size_t)b * SEQ_N + i0w) * DIM_V;
#pragma unroll
    for (int r = 0; r < 4; ++r) {
      float inv = 1.0f / l[r];
      int row = qd * 4 + r;
#pragma unroll
      for (int vt = 0; vt < 8; ++vt)
        Ob[(size_t)row * DIM_V + vt * 16 + nn] = o[vt][r] * inv;
    }
  } else {
    const int p = b * 16 + (rt - 16);
    const int slot = p * 2 + c;
    float* Op = ws + (size_t)slot * 64 * 128;
#pragma unroll
    for (int r = 0; r < 4; ++r) {
      int row = w * 16 + qd * 4 + r;
#pragma unroll
      for (int vt = 0; vt < 8; ++vt)
        Op[(size_t)row * 128 + vt * 16 + nn] = o[vt][r];
    }
    if (nn == 0) {
#pragma unroll
      for (int r = 0; r < 4; ++r) {
        int row = w * 16 + qd * 4 + r;
        ws[WS_M_OFF + slot * 64 + row] = m[r];
        ws[WS_L_OFF + slot * 64 + row] = l[r];
      }
    }
  }
}

// 768 wgs: u<16 -> (rt=16+u, chunk0, 16 tiles); u in [16,32) -> (rt=47-u, chunk1);
// u in [32,48) -> (rt=47-u, whole row, direct). Long chunks dispatched first.
__global__ __launch_bounds__(256, 2)
void fa_chunk(const float* __restrict__ Q, const float* __restrict__ K,
              const float* __restrict__ Vg, const int* __restrict__ kpl,
              const int* __restrict__ amask, float* __restrict__ Out,
              float* __restrict__ ws) {
  __shared__ __align__(16) ushort_t smem[SMEM_ELEMS];
  const int bx = blockIdx.x;
  const int b  = bx & 15;
  const int u  = bx >> 4;
  int rt, c;
  if (u < 16)      { rt = 16 + u; c = 0; }
  else if (u < 32) { rt = 47 - u; c = 1; }
  else             { rt = 47 - u; c = 0; }
  const int flag   = amask[0];
  const int mlimit = SEQ_M - kpl[b];
  const int ntiles = flag ? (rt + 1) : (SEQ_M / BC);
  const int jt_lo  = (c == 1) ? 16 : 0;
  const int jt_hi  = (c == 0 && rt >= 16) ? 16 : ntiles;
  process_chunk(Q, K, Vg, Out, ws, smem, b, rt, jt_lo, jt_hi, mlimit, flag, c, rt < 16);
}

// merge split rows: exp2-domain flash combine
__global__ __launch_bounds__(256)
void fa_merge(const float* __restrict__ ws, float* __restrict__ Out) {
  const int w = threadIdx.x >> 6, lane = threadIdx.x & 63;
  const int rowid = blockIdx.x * 4 + w;        // 0..16383
  const int p = rowid >> 6, rr = rowid & 63;
  const int b = p >> 4, rt = 16 + (p & 15);
  float m1 = ws[WS_M_OFF + (p * 2 + 0) * 64 + rr];
  float l1 = ws[WS_L_OFF + (p * 2 + 0) * 64 + rr];
  float m2 = ws[WS_M_OFF + (p * 2 + 1) * 64 + rr];
  float l2 = ws[WS_L_OFF + (p * 2 + 1) * 64 + rr];
  float M  = fmaxf(m1, m2);
  float a1 = EXP2F(m1 - M), a2 = EXP2F(m2 - M);
  float inv = 1.0f / (l1 * a1 + l2 * a2);
  const float* O1 = ws + ((size_t)(p * 2 + 0) * 64 + rr) * 128;
  const float* O2 = ws + ((size_t)(p * 2 + 1) * 64 + rr) * 128;
  float2 x1 = *(const float2*)(O1 + lane * 2);
  float2 x2 = *(const float2*)(O2 + lane * 2);
  float2 r;
  r.x = (x1.x * a1 + x2.x * a2) * inv;
  r.y = (x1.y * a1 + x2.y * a2) * inv;
  *(float2*)(Out + ((size_t)b * SEQ_N + rt * 64 + rr) * 128 + lane * 2) = r;
}

// fallback (ws too small): round-5 paired uniform wgs, direct writes only
__global__ __launch_bounds__(256, 2)
void fa_paired(const float* __restrict__ Q, const float* __restrict__ K,
               const float* __restrict__ Vg, const int* __restrict__ kpl,
               const int* __restrict__ amask, float* __restrict__ Out) {
  __shared__ __align__(16) ushort_t smem[SMEM_ELEMS];
  const int bx = blockIdx.x;
  const int b  = bx & 15;
  const int pp = bx >> 4;
  const int flag   = amask[0];
  const int mlimit = SEQ_M - kpl[b];
#pragma unroll 1
  for (int ph = 0; ph < 2; ++ph) {
    const int rt = ph ? (31 - pp) : pp;
    const int ntiles = flag ? (rt + 1) : (SEQ_M / BC);
    process_chunk(Q, K, Vg, Out, nullptr, smem, b, rt, 0, ntiles, mlimit, flag, 0, true);
  }
}

extern "C" void kernel_launch(void* const* d_in, const int* in_sizes, int n_in,
                              void* d_out, int out_size, void* d_ws, size_t ws_size,
                              hipStream_t stream) {
  const float* Q   = (const float*)d_in[0];
  const float* K   = (const float*)d_in[1];
  const float* V   = (const float*)d_in[2];
  const int* kpl   = (const int*)d_in[3];
  const int* amask = (const int*)d_in[4];
  float* O         = (float*)d_out;
  float* ws        = (float*)d_ws;

  if (ws_size >= (size_t)WS_FLOATS * 4) {
    hipLaunchKernelGGL(fa_chunk, dim3(768), dim3(256), 0, stream, Q, K, V, kpl, amask, O, ws);
    hipLaunchKernelGGL(fa_merge, dim3(4096), dim3(256), 0, stream, ws, O);
  } else {
    hipLaunchKernelGGL(fa_paired, dim3(256), dim3(256), 0, stream, Q, K, V, kpl, amask, O);
  }
}